// Round 5
// baseline (93.839 us; speedup 1.0000x reference)
//
#include <hip/hip_runtime.h>

#define BLOCK 256
#define IPT   2                 // i-values per thread
#define JS    128               // j-columns per block
#define ITILE (BLOCK * IPT)     // 512 = i-superblock height
#define JT_PER_I (ITILE / JS)   // 4 j-tiles per i-superblock
#define NBLOCKS 2112            // sum_{bi<32} 4*(bi+1)
#define RBLOCK 1024

// M_ij = clip(p_i-p_j)*clip(t_i-t_j) is symmetric. i-superblocks of 512 rows;
// j-tiles of 128 cols. Tiles strictly left of the diagonal band: weight 2;
// diagonal-band tiles: weight 1 (computed whole, no per-pair predicate).
// loss = 1 - S/(n*(n-1)).
//
// R5 structure: NO LDS, NO barriers, NO atomics. j-values are block-uniform
// -> scalar loads (SMEM pipe), operands broadcast from SGPRs. 1-D grid of
// exactly the working tiles (triangular decode). Each wave writes its own
// partial; tiny second kernel reduces.
__global__ __launch_bounds__(BLOCK, 8) void kendall_pairs(
    const float* __restrict__ p, const float* __restrict__ t,
    float* __restrict__ partial, int n) {
    // decode slot s = 2*bi*(bi+1) + bj  (bj < 4*(bi+1))
    const int s = blockIdx.x;
    int bi = (int)((__builtin_sqrtf(2.0f * (float)s + 1.0f) - 1.0f) * 0.5f);
    while (2 * (bi + 1) * (bi + 2) <= s) ++bi;   // fixup fp rounding
    while (2 * bi * (bi + 1) > s) --bi;
    const int bj = s - 2 * bi * (bi + 1);
    const float w = (bj < JT_PER_I * bi) ? 2.0f : 1.0f;

    const int i0 = bi * ITILE;
    const int j0 = bj * JS;

    float2 pit[IPT];
#pragma unroll
    for (int u = 0; u < IPT; ++u) {
        int i = i0 + u * BLOCK + threadIdx.x;     // coalesced per u; n=16384 => always in range
        pit[u] = make_float2(p[i], t[i]);
    }

    const float* __restrict__ pj = p + j0;        // block-uniform bases
    const float* __restrict__ tj = t + j0;

    float a[IPT * 2] = {0.0f, 0.0f, 0.0f, 0.0f};  // 4 independent fmac chains

#pragma unroll 8
    for (int k = 0; k < JS; k += 2) {
        // uniform indices -> scalar loads (s_load_dwordx2), SGPR broadcast
        float pj0 = pj[k], pj1 = pj[k + 1];
        float tj0 = tj[k], tj1 = tj[k + 1];
#pragma unroll
        for (int u = 0; u < IPT; ++u) {
            float pd0 = __builtin_amdgcn_fmed3f(pit[u].x - pj0, -1.0f, 1.0f);
            float td0 = __builtin_amdgcn_fmed3f(pit[u].y - tj0, -1.0f, 1.0f);
            a[2 * u]     = fmaf(pd0, td0, a[2 * u]);
            float pd1 = __builtin_amdgcn_fmed3f(pit[u].x - pj1, -1.0f, 1.0f);
            float td1 = __builtin_amdgcn_fmed3f(pit[u].y - tj1, -1.0f, 1.0f);
            a[2 * u + 1] = fmaf(pd1, td1, a[2 * u + 1]);
        }
    }

    float r = (a[0] + a[1]) + (a[2] + a[3]);
#pragma unroll
    for (int off = 32; off > 0; off >>= 1) r += __shfl_down(r, off, 64);

    if ((threadIdx.x & 63) == 0)                  // one store per wave, no block reduce
        partial[blockIdx.x * (BLOCK / 64) + (threadIdx.x >> 6)] = w * r;
}

// One block: reduce nPartial floats (L2-resident) -> loss.
__global__ __launch_bounds__(RBLOCK) void kendall_reduce(
    const float* __restrict__ partial, float* __restrict__ out,
    int nPartial, int n) {
    __shared__ float wsum[RBLOCK / 64];
    float s = 0.0f;
    for (int k = threadIdx.x; k < nPartial; k += RBLOCK) s += partial[k];
#pragma unroll
    for (int off = 32; off > 0; off >>= 1) s += __shfl_down(s, off, 64);
    const int lane = threadIdx.x & 63;
    const int wid  = threadIdx.x >> 6;
    if (lane == 0) wsum[wid] = s;
    __syncthreads();
    if (threadIdx.x == 0) {
        float S = 0.0f;
#pragma unroll
        for (int v2 = 0; v2 < RBLOCK / 64; ++v2) S += wsum[v2];
        float denom = (float)n * (float)(n - 1);
        out[0] = 1.0f - S / denom;
    }
}

extern "C" void kernel_launch(void* const* d_in, const int* in_sizes, int n_in,
                              void* d_out, int out_size, void* d_ws, size_t ws_size,
                              hipStream_t stream) {
    const float* predict = (const float*)d_in[0];
    const float* target  = (const float*)d_in[1];
    float* out = (float*)d_out;
    float* partial = (float*)d_ws;               // 2112*4 slots, all written each call
    const int n = in_sizes[0];                   // 16384

    const int nPartial = NBLOCKS * (BLOCK / 64); // 8448
    kendall_pairs<<<NBLOCKS, BLOCK, 0, stream>>>(predict, target, partial, n);
    kendall_reduce<<<1, RBLOCK, 0, stream>>>(partial, out, nPartial, n);
}

// Round 6
// 80.539 us; speedup vs baseline: 1.1651x; 1.1651x over previous
//
#include <hip/hip_runtime.h>

#define BLOCK 512               // 8 waves
#define IPT   2                 // i-values per thread
#define ITILE 1024              // i-superblock height (16 superblocks)
#define JS    128               // j-slice per tile
#define JT_PER_I 8              // ITILE/JS
#define NT    1088              // sum_{bi<16} 8*(bi+1) working tiles
#define GRID  256               // exactly 1 block per CU, ONE dispatch round
#define RBLOCK 1024

// M_ij = clip(p_i-p_j)*clip(t_i-t_j) is symmetric. Tiles (bi,bj): 1024 rows x
// 128 cols; strictly-left-of-diagonal-band tiles weight 2, band tiles weight 1
// (computed whole -> no per-pair predicate). loss = 1 - S/(n*(n-1)).
//
// R6: quasi-persistent. 256 workgroups grid-stride over the 1088 tiles with
// register ping-pong prefetch (next i-regs + j-slice loaded during current
// tile's compute), ONE barrier per tile, LDS float4 broadcast j-reads.
// Rationale: R1-R5 showed pairs time ~invariant to pair count with low
// VALUBusy/occupancy -> per-workgroup fixed costs dominate; pay them 256x.

__device__ __forceinline__ void decode_tile(int s, int& bi, int& bj, float& w) {
    int b = (int)((__builtin_sqrtf((float)s + 1.0f) - 1.0f) * 0.5f);
    while (4 * (b + 1) * (b + 2) <= s) ++b;      // fixup fp rounding
    while (4 * b * (b + 1) > s) --b;
    bi = b;
    bj = s - 4 * b * (b + 1);
    w = (bj < JT_PER_I * b) ? 2.0f : 1.0f;
}

__global__ __launch_bounds__(BLOCK) void kendall_pairs(
    const float* __restrict__ p, const float* __restrict__ t,
    float* __restrict__ partial, int n) {
    __shared__ float2 sj[2][JS];                 // ping-pong j-slices

    int s = blockIdx.x;
    int bi, bj; float w;
    decode_tile(s, bi, bj, w);

    // first tile: stage j-slice + load i-regs
    if (threadIdx.x < JS) {
        int j = bj * JS + threadIdx.x;
        sj[0][threadIdx.x] = make_float2(p[j], t[j]);
    }
    float2 pit[IPT];
#pragma unroll
    for (int u = 0; u < IPT; ++u) {
        int i = bi * ITILE + u * BLOCK + threadIdx.x;   // coalesced; n=16384 exact
        pit[u] = make_float2(p[i], t[i]);
    }
    __syncthreads();

    float acc = 0.0f;
    int buf = 0;
    for (;;) {
        const int sn = s + GRID;
        const bool more = (sn < NT);

        // prefetch next tile into registers (latency hidden under compute)
        int nbi = 0, nbj = 0; float nw = 0.0f;
        float2 npit[IPT]; float2 njv = make_float2(0.0f, 0.0f);
        if (more) {
            decode_tile(sn, nbi, nbj, nw);
#pragma unroll
            for (int u = 0; u < IPT; ++u) {
                int i = nbi * ITILE + u * BLOCK + threadIdx.x;
                npit[u] = make_float2(p[i], t[i]);
            }
            if (threadIdx.x < JS) {
                int j = nbj * JS + threadIdx.x;
                njv = make_float2(p[j], t[j]);
            }
        }

        // compute current tile: 4 independent fmac chains, float4 LDS broadcast
        float a0 = 0.0f, a1 = 0.0f, a2 = 0.0f, a3 = 0.0f;
        const float4* j4 = reinterpret_cast<const float4*>(sj[buf]);
#pragma unroll 8
        for (int g = 0; g < JS / 2; ++g) {
            float4 jv = j4[g];                   // uniform addr -> broadcast
            float pd0 = __builtin_amdgcn_fmed3f(pit[0].x - jv.x, -1.0f, 1.0f);
            float td0 = __builtin_amdgcn_fmed3f(pit[0].y - jv.y, -1.0f, 1.0f);
            a0 = fmaf(pd0, td0, a0);
            float pd1 = __builtin_amdgcn_fmed3f(pit[0].x - jv.z, -1.0f, 1.0f);
            float td1 = __builtin_amdgcn_fmed3f(pit[0].y - jv.w, -1.0f, 1.0f);
            a1 = fmaf(pd1, td1, a1);
            float pd2 = __builtin_amdgcn_fmed3f(pit[1].x - jv.x, -1.0f, 1.0f);
            float td2 = __builtin_amdgcn_fmed3f(pit[1].y - jv.y, -1.0f, 1.0f);
            a2 = fmaf(pd2, td2, a2);
            float pd3 = __builtin_amdgcn_fmed3f(pit[1].x - jv.z, -1.0f, 1.0f);
            float td3 = __builtin_amdgcn_fmed3f(pit[1].y - jv.w, -1.0f, 1.0f);
            a3 = fmaf(pd3, td3, a3);
        }
        acc = fmaf(w, (a0 + a1) + (a2 + a3), acc);

        if (!more) break;

        // publish prefetched j-slice into the other buffer; one barrier/tile.
        // (Safe: the barrier below also fences the NEXT iteration's write of
        // the current buf, which all waves finished reading just above.)
        if (threadIdx.x < JS) sj[buf ^ 1][threadIdx.x] = njv;
        __syncthreads();
        buf ^= 1;
        s = sn; bi = nbi; bj = nbj; w = nw;
        pit[0] = npit[0]; pit[1] = npit[1];
    }

    // per-wave reduce, one store per wave — no block reduce, no extra barrier
    float r = acc;
#pragma unroll
    for (int off = 32; off > 0; off >>= 1) r += __shfl_down(r, off, 64);
    if ((threadIdx.x & 63) == 0)
        partial[blockIdx.x * (BLOCK / 64) + (threadIdx.x >> 6)] = r;
}

// One block: reduce nPartial floats (L2-resident) -> loss.
__global__ __launch_bounds__(RBLOCK) void kendall_reduce(
    const float* __restrict__ partial, float* __restrict__ out,
    int nPartial, int n) {
    __shared__ float wsum[RBLOCK / 64];
    float s = 0.0f;
    for (int k = threadIdx.x; k < nPartial; k += RBLOCK) s += partial[k];
#pragma unroll
    for (int off = 32; off > 0; off >>= 1) s += __shfl_down(s, off, 64);
    const int lane = threadIdx.x & 63;
    const int wid  = threadIdx.x >> 6;
    if (lane == 0) wsum[wid] = s;
    __syncthreads();
    if (threadIdx.x == 0) {
        float S = 0.0f;
#pragma unroll
        for (int v2 = 0; v2 < RBLOCK / 64; ++v2) S += wsum[v2];
        float denom = (float)n * (float)(n - 1);
        out[0] = 1.0f - S / denom;
    }
}

extern "C" void kernel_launch(void* const* d_in, const int* in_sizes, int n_in,
                              void* d_out, int out_size, void* d_ws, size_t ws_size,
                              hipStream_t stream) {
    const float* predict = (const float*)d_in[0];
    const float* target  = (const float*)d_in[1];
    float* out = (float*)d_out;
    float* partial = (float*)d_ws;               // GRID*8 slots, all written each call
    const int n = in_sizes[0];                   // 16384

    const int nPartial = GRID * (BLOCK / 64);    // 2048
    kendall_pairs<<<GRID, BLOCK, 0, stream>>>(predict, target, partial, n);
    kendall_reduce<<<1, RBLOCK, 0, stream>>>(partial, out, nPartial, n);
}

// Round 7
// 79.065 us; speedup vs baseline: 1.1869x; 1.0186x over previous
//
#include <hip/hip_runtime.h>

#define BLOCK 512               // 8 waves/block
#define IPT   4                 // i-values per thread
#define ITILE 2048              // BLOCK*IPT rows per tile
#define JS    128               // j-columns per tile
#define JT_PER_I 16             // ITILE/JS
#define NT    576               // sum_{bi<8} 16*(bi+1) working tiles == grid size
#define RBLOCK 1024

// M_ij = clip(p_i-p_j)*clip(t_i-t_j) is symmetric. Tiles: 2048 rows x 128
// cols. Tiles strictly left of the diagonal band: weight 2; band tiles:
// weight 1 (computed whole, no per-pair predicate). loss = 1 - S/(n*(n-1)).
//
// R7: one tile per block, grid == working tiles (576). All blocks co-resident
// (294912 threads, 1KB LDS, low VGPR) -> ~4.5 waves/SIMD from t=0, no
// steady-state loops/decodes, ONE barrier, IPT=4 so VALU:LDS = 80:12 cycles
// per ds_read_b128 (comfortably VALU-bound).
__global__ __launch_bounds__(BLOCK) void kendall_pairs(
    const float* __restrict__ p, const float* __restrict__ t,
    float* __restrict__ partial, int n) {
    __shared__ float2 sj[JS];

    // decode s = 8*bi*(bi+1) + bj, bj < 16*(bi+1)
    const int s = blockIdx.x;
    int bi = (int)((__builtin_sqrtf(4.0f + 2.0f * (float)s) - 2.0f) * 0.25f);
    while (8 * (bi + 1) * (bi + 2) <= s) ++bi;   // fp-rounding fixup
    while (8 * bi * (bi + 1) > s) --bi;
    const int bj = s - 8 * bi * (bi + 1);
    const float w = (bj < JT_PER_I * bi) ? 2.0f : 1.0f;

    if (threadIdx.x < JS) {
        int j = bj * JS + threadIdx.x;
        sj[threadIdx.x] = make_float2(p[j], t[j]);
    }

    float2 pit[IPT];
#pragma unroll
    for (int u = 0; u < IPT; ++u) {
        int i = bi * ITILE + u * BLOCK + threadIdx.x;  // coalesced; n=16384 exact
        pit[u] = make_float2(p[i], t[i]);
    }
    __syncthreads();

    float a[2 * IPT] = {0.0f};                   // 8 independent fmac chains
    const float4* j4 = reinterpret_cast<const float4*>(sj);
#pragma unroll 4
    for (int g = 0; g < JS / 2; ++g) {
        float4 jv = j4[g];                       // uniform addr -> LDS broadcast
#pragma unroll
        for (int u = 0; u < IPT; ++u) {
            float pd0 = __builtin_amdgcn_fmed3f(pit[u].x - jv.x, -1.0f, 1.0f);
            float td0 = __builtin_amdgcn_fmed3f(pit[u].y - jv.y, -1.0f, 1.0f);
            a[2 * u]     = fmaf(pd0, td0, a[2 * u]);
            float pd1 = __builtin_amdgcn_fmed3f(pit[u].x - jv.z, -1.0f, 1.0f);
            float td1 = __builtin_amdgcn_fmed3f(pit[u].y - jv.w, -1.0f, 1.0f);
            a[2 * u + 1] = fmaf(pd1, td1, a[2 * u + 1]);
        }
    }

    float r = ((a[0] + a[1]) + (a[2] + a[3])) + ((a[4] + a[5]) + (a[6] + a[7]));
#pragma unroll
    for (int off = 32; off > 0; off >>= 1) r += __shfl_down(r, off, 64);

    if ((threadIdx.x & 63) == 0)                 // one store/wave; no 2nd barrier
        partial[blockIdx.x * (BLOCK / 64) + (threadIdx.x >> 6)] = w * r;
}

// One block: reduce nPartial floats (L2-resident) -> loss.
__global__ __launch_bounds__(RBLOCK) void kendall_reduce(
    const float* __restrict__ partial, float* __restrict__ out,
    int nPartial, int n) {
    __shared__ float wsum[RBLOCK / 64];
    float s = 0.0f;
    for (int k = threadIdx.x; k < nPartial; k += RBLOCK) s += partial[k];
#pragma unroll
    for (int off = 32; off > 0; off >>= 1) s += __shfl_down(s, off, 64);
    const int lane = threadIdx.x & 63;
    const int wid  = threadIdx.x >> 6;
    if (lane == 0) wsum[wid] = s;
    __syncthreads();
    if (threadIdx.x == 0) {
        float S = 0.0f;
#pragma unroll
        for (int v2 = 0; v2 < RBLOCK / 64; ++v2) S += wsum[v2];
        float denom = (float)n * (float)(n - 1);
        out[0] = 1.0f - S / denom;
    }
}

extern "C" void kernel_launch(void* const* d_in, const int* in_sizes, int n_in,
                              void* d_out, int out_size, void* d_ws, size_t ws_size,
                              hipStream_t stream) {
    const float* predict = (const float*)d_in[0];
    const float* target  = (const float*)d_in[1];
    float* out = (float*)d_out;
    float* partial = (float*)d_ws;               // NT*8 slots, all written each call
    const int n = in_sizes[0];                   // 16384

    const int nPartial = NT * (BLOCK / 64);      // 4608
    kendall_pairs<<<NT, BLOCK, 0, stream>>>(predict, target, partial, n);
    kendall_reduce<<<1, RBLOCK, 0, stream>>>(partial, out, nPartial, n);
}